// Round 1
// baseline (691.352 us; speedup 1.0000x reference)
//
#include <hip/hip_runtime.h>
#include <stdint.h>

typedef __attribute__((ext_vector_type(8))) short short8;
typedef __attribute__((ext_vector_type(4))) float f32x4;

#define DEVI __device__ __forceinline__

// float -> bf16 bits, round-to-nearest-even
DEVI unsigned short f2b(float f) {
  union { float f; unsigned u; } v; v.f = f;
  return (unsigned short)((v.u + 0x7fffu + ((v.u >> 16) & 1u)) >> 16);
}

DEVI uint2 pack4(f32x4 a) {
  uint2 o;
  o.x = (unsigned)f2b(a[0]) | ((unsigned)f2b(a[1]) << 16);
  o.y = (unsigned)f2b(a[2]) | ((unsigned)f2b(a[3]) << 16);
  return o;
}

// async global->LDS, 16B per lane; LDS dest must be wave-uniform base + lane*16
#define GLD16(g, s) __builtin_amdgcn_global_load_lds( \
    (const __attribute__((address_space(1))) void*)(g), \
    (__attribute__((address_space(3))) void*)(s), 16, 0, 0)

// ---------------------------------------------------------------------------
// Pool: x1 [8][768][128][128] f32 --4x4 mean--> x1fT [8*1024][768] bf16 (transposed!)
// grid (96 c-chunks, 32 ho, 8 b), block 256
__global__ __launch_bounds__(256) void pool_kernel(const float* __restrict__ x1,
                                                   unsigned short* __restrict__ x1fT) {
  const int cchunk = blockIdx.x;
  const int ho = blockIdx.y;
  const int b = blockIdx.z;
  const int tid = threadIdx.x;
  const int ci = tid >> 5, wo = tid & 31;
  const int c = cchunk * 8 + ci;
  const float* base = x1 + ((size_t)(b * 768 + c) * 128 + ho * 4) * 128 + wo * 4;
  float s = 0.f;
#pragma unroll
  for (int i = 0; i < 4; ++i) {
    f32x4 v = *reinterpret_cast<const f32x4*>(base + (size_t)i * 128);
    s += v[0] + v[1] + v[2] + v[3];
  }
  __shared__ float tile[8][33];
  tile[ci][wo] = s * 0.0625f;
  __syncthreads();
  const int wo2 = tid >> 3, ci2 = tid & 7;
  x1fT[(size_t)(b * 1024 + ho * 32 + wo2) * 768 + cchunk * 8 + ci2] = f2b(tile[ci2][wo2]);
}

// ---------------------------------------------------------------------------
// Transpose x2 [8][768][1024] f32 -> x2fT [8*1024][768] bf16
// grid (12 c-tiles, 32 n-tiles, 8 b), block 256
__global__ __launch_bounds__(256) void x2t_kernel(const float* __restrict__ x2,
                                                  unsigned short* __restrict__ x2fT) {
  const int ct = blockIdx.x;
  const int nt = blockIdx.y;
  const int b = blockIdx.z;
  const int tid = threadIdx.x;
  __shared__ float tile[64][33];
  {
    const int nl = tid & 31, cb = tid >> 5;
#pragma unroll
    for (int p = 0; p < 8; ++p) {
      const int cl = p * 8 + cb;
      tile[cl][nl] = x2[(size_t)(b * 768 + ct * 64 + cl) * 1024 + nt * 32 + nl];
    }
  }
  __syncthreads();
  {
    const int c2 = tid & 63, nb = tid >> 6;
#pragma unroll
    for (int p = 0; p < 8; ++p) {
      const int nl = p * 4 + nb;
      x2fT[(size_t)(b * 1024 + nt * 32 + nl) * 768 + ct * 64 + c2] = f2b(tile[c2][nl]);
    }
  }
}

// ---------------------------------------------------------------------------
// Convert Wq/Wk/Wv f32 [768][768] -> bf16 (same layout). 147456 float4s, grid 576.
__global__ __launch_bounds__(256) void wconv_kernel(
    const f32x4* __restrict__ Wq, const f32x4* __restrict__ Wk, const f32x4* __restrict__ Wv,
    uint2* __restrict__ Wqb, uint2* __restrict__ Wkb, uint2* __restrict__ Wvb) {
  const int i = blockIdx.x * 256 + threadIdx.x;
  Wqb[i] = pack4(Wq[i]);
  Wkb[i] = pack4(Wk[i]);
  Wvb[i] = pack4(Wv[i]);
}

// ---------------------------------------------------------------------------
// NT GEMM: C[M][N] = A[M][K] * B[N][K]^T, bf16 in, f32 accum.
// 128x128 tile, BK=32, 4 waves, 16x16x32 MFMA, global_load_lds staging (m97 structure).
// EPI: 0 = store bf16; 1 = store f32 * scale; 2 = store f32 + resid (residual add)
template <int EPI>
__global__ __launch_bounds__(256) void gemm_nt(
    const unsigned short* __restrict__ A, const unsigned short* __restrict__ B,
    void* __restrict__ Cv, const float* __restrict__ resid,
    int K, int lda, int ldb, int ldc,
    long long sA, long long sB, long long sC, long long sR, float scale) {
  const int bn = blockIdx.x, bm = blockIdx.y, bz = blockIdx.z;
  A += (long long)bz * sA;
  B += (long long)bz * sB;
  const int tid = threadIdx.x;
  const int wave = tid >> 6, lane = tid & 63;
  const int wm = wave >> 1, wn = wave & 1;

  __shared__ unsigned short As[128 * 32];
  __shared__ unsigned short Bs[128 * 32];

  f32x4 acc[4][4] = {};

  // staging geometry: each wave stages 32 rows (2x16) of each tile, 16B per lane per load
  const int r0 = wave * 32 + (lane >> 2);
  const int c0 = (lane & 3) * 8;
  const unsigned short* ga = A + (size_t)(bm * 128 + r0) * lda + c0;
  const unsigned short* gb = B + (size_t)(bn * 128 + r0) * ldb + c0;
  unsigned short* sa = As + wave * 1024 + lane * 8;
  unsigned short* sb = Bs + wave * 1024 + lane * 8;
  const size_t stepA16 = (size_t)16 * lda;
  const size_t stepB16 = (size_t)16 * ldb;

  const int rowa = wm * 64 + (lane & 15);
  const int rowb = wn * 64 + (lane & 15);
  const int kch = (lane >> 4) * 8;

  const int nK = K >> 5;
  for (int kt = 0; kt < nK; ++kt) {
    GLD16(ga, sa);
    GLD16(ga + stepA16, sa + 512);
    GLD16(gb, sb);
    GLD16(gb + stepB16, sb + 512);
    ga += 32;
    gb += 32;
    __syncthreads();  // drains vmcnt before barrier -> LDS tile ready
    short8 af[4], bq[4];
#pragma unroll
    for (int mi = 0; mi < 4; ++mi)
      af[mi] = *reinterpret_cast<const short8*>(&As[(rowa + mi * 16) * 32 + kch]);
#pragma unroll
    for (int ni = 0; ni < 4; ++ni)
      bq[ni] = *reinterpret_cast<const short8*>(&Bs[(rowb + ni * 16) * 32 + kch]);
#pragma unroll
    for (int mi = 0; mi < 4; ++mi)
#pragma unroll
      for (int ni = 0; ni < 4; ++ni)
        acc[mi][ni] = __builtin_amdgcn_mfma_f32_16x16x32_bf16(af[mi], bq[ni], acc[mi][ni], 0, 0, 0);
    __syncthreads();  // all waves done reading before next stage overwrites
  }

  // epilogue: C/D layout col = lane&15, row = (lane>>4)*4 + reg  [m89-verified]
  const int cc = lane & 15, rr = (lane >> 4) * 4;
  const int rbase = bm * 128 + wm * 64, cbase = bn * 128 + wn * 64;
  if constexpr (EPI == 0) {
    unsigned short* C = (unsigned short*)Cv + (long long)bz * sC;
#pragma unroll
    for (int mi = 0; mi < 4; ++mi)
#pragma unroll
      for (int ni = 0; ni < 4; ++ni)
#pragma unroll
        for (int r = 0; r < 4; ++r)
          C[(size_t)(rbase + mi * 16 + rr + r) * ldc + (cbase + ni * 16 + cc)] =
              f2b(acc[mi][ni][r]);
  } else if constexpr (EPI == 1) {
    float* C = (float*)Cv + (long long)bz * sC;
#pragma unroll
    for (int mi = 0; mi < 4; ++mi)
#pragma unroll
      for (int ni = 0; ni < 4; ++ni)
#pragma unroll
        for (int r = 0; r < 4; ++r)
          C[(size_t)(rbase + mi * 16 + rr + r) * ldc + (cbase + ni * 16 + cc)] =
              acc[mi][ni][r] * scale;
  } else {
    float* C = (float*)Cv + (long long)bz * sC;
    const float* R = resid + (long long)bz * sR;
#pragma unroll
    for (int mi = 0; mi < 4; ++mi)
#pragma unroll
      for (int ni = 0; ni < 4; ++ni)
#pragma unroll
        for (int r = 0; r < 4; ++r) {
          const size_t idx = (size_t)(rbase + mi * 16 + rr + r) * ldc + (cbase + ni * 16 + cc);
          C[idx] = acc[mi][ni][r] + R[idx];
        }
  }
}

// ---------------------------------------------------------------------------
// Row softmax: S [6144 rows][768] f32 -> P bf16, one wave per row
__global__ __launch_bounds__(256) void softmax_kernel(const float* __restrict__ S,
                                                      unsigned short* __restrict__ P) {
  const int row = blockIdx.x * 4 + (threadIdx.x >> 6);
  const int lane = threadIdx.x & 63;
  const float* r = S + (size_t)row * 768;
  f32x4 v[3];
  float mx = -1e30f;
#pragma unroll
  for (int i = 0; i < 3; ++i) {
    v[i] = *reinterpret_cast<const f32x4*>(r + (i * 64 + lane) * 4);
    mx = fmaxf(fmaxf(fmaxf(v[i][0], v[i][1]), fmaxf(v[i][2], v[i][3])), mx);
  }
#pragma unroll
  for (int off = 32; off > 0; off >>= 1) mx = fmaxf(mx, __shfl_xor(mx, off));
  float sum = 0.f;
#pragma unroll
  for (int i = 0; i < 3; ++i)
#pragma unroll
    for (int j = 0; j < 4; ++j) {
      v[i][j] = __expf(v[i][j] - mx);
      sum += v[i][j];
    }
#pragma unroll
  for (int off = 32; off > 0; off >>= 1) sum += __shfl_xor(sum, off);
  const float inv = 1.f / sum;
  unsigned short* p = P + (size_t)row * 768;
#pragma unroll
  for (int i = 0; i < 3; ++i) {
    uint2 o;
    o.x = (unsigned)f2b(v[i][0] * inv) | ((unsigned)f2b(v[i][1] * inv) << 16);
    o.y = (unsigned)f2b(v[i][2] * inv) | ((unsigned)f2b(v[i][3] * inv) << 16);
    *reinterpret_cast<uint2*>(p + (i * 64 + lane) * 4) = o;
  }
}

// ---------------------------------------------------------------------------
extern "C" void kernel_launch(void* const* d_in, const int* in_sizes, int n_in,
                              void* d_out, int out_size, void* d_ws, size_t ws_size,
                              hipStream_t stream) {
  const float* x1 = (const float*)d_in[0];  // [8][768][128][128]
  const float* x2 = (const float*)d_in[1];  // [8][768][32][32]
  const float* Wq = (const float*)d_in[2];  // [768][768]
  const float* Wk = (const float*)d_in[3];
  const float* Wv = (const float*)d_in[4];
  float* out = (float*)d_out;  // [8][768][32][32]

  char* ws = (char*)d_ws;
  size_t off = 0;
  auto alloc = [&](size_t bytes) {
    char* p = ws + off;
    off += (bytes + 255) & ~(size_t)255;
    return p;
  };
  unsigned short* x1fT = (unsigned short*)alloc((size_t)8192 * 768 * 2);  // [b*n][c1]
  unsigned short* x2fT = (unsigned short*)alloc((size_t)8192 * 768 * 2);  // [b*n][c2]
  unsigned short* Wqb = (unsigned short*)alloc((size_t)589824 * 2);
  unsigned short* Wkb = (unsigned short*)alloc((size_t)589824 * 2);
  unsigned short* Wvb = (unsigned short*)alloc((size_t)589824 * 2);
  unsigned short* qb = (unsigned short*)alloc((size_t)768 * 8192 * 2);   // [c2][b*n]
  unsigned short* kb = (unsigned short*)alloc((size_t)768 * 8192 * 2);   // [c1][b*n]
  unsigned short* vTb = (unsigned short*)alloc((size_t)8192 * 768 * 2);  // [b*n][c1]
  float* attnf = (float*)alloc((size_t)8 * 768 * 768 * 4);               // [b][c2][c1]
  unsigned short* attnb = x2fT;  // overlay: x2fT dead after q-GEMM

  // 1. pool + transpose x1 -> x1fT bf16
  pool_kernel<<<dim3(96, 32, 8), 256, 0, stream>>>(x1, x1fT);
  // 2. transpose x2 -> x2fT bf16
  x2t_kernel<<<dim3(12, 32, 8), 256, 0, stream>>>(x2, x2fT);
  // 3. weights -> bf16
  wconv_kernel<<<dim3(576), 256, 0, stream>>>((const f32x4*)Wq, (const f32x4*)Wk,
                                              (const f32x4*)Wv, (uint2*)Wqb, (uint2*)Wkb,
                                              (uint2*)Wvb);
  // 4. k = Wk * x1f   [768][8192]
  gemm_nt<0><<<dim3(64, 6, 1), 256, 0, stream>>>(Wkb, x1fT, kb, nullptr, 768, 768, 768, 8192,
                                                 0, 0, 0, 0, 1.f);
  // 5. q = Wq * x2f   [768][8192]
  gemm_nt<0><<<dim3(64, 6, 1), 256, 0, stream>>>(Wqb, x2fT, qb, nullptr, 768, 768, 768, 8192,
                                                 0, 0, 0, 0, 1.f);
  // 6. vT = x1fT * Wv^T   [8192][768]
  gemm_nt<0><<<dim3(6, 64, 1), 256, 0, stream>>>(x1fT, Wvb, vTb, nullptr, 768, 768, 768, 768,
                                                 0, 0, 0, 0, 1.f);
  // 7. attn[b] = q[b] * k[b]^T / 32   [768][768] f32, K=1024 (contract over n)
  gemm_nt<1><<<dim3(6, 6, 8), 256, 0, stream>>>(qb, kb, attnf, nullptr, 1024, 8192, 8192, 768,
                                                1024, 1024, 589824, 0, 1.f / 32.f);
  // 8. softmax rows -> bf16
  softmax_kernel<<<dim3(1536), 256, 0, stream>>>(attnf, attnb);
  // 9. out[b] = attn[b] * v[b] + x2   [768][1024] f32 -> d_out
  gemm_nt<2><<<dim3(8, 6, 8), 256, 0, stream>>>(attnb, vTb, out, x2, 768, 768, 768, 1024,
                                                589824, 786432, 786432, 786432, 1.f);
}

// Round 3
// 659.875 us; speedup vs baseline: 1.0477x; 1.0477x over previous
//
#include <hip/hip_runtime.h>
#include <stdint.h>

typedef __attribute__((ext_vector_type(8))) short short8;
typedef __attribute__((ext_vector_type(4))) float f32x4;

#define DEVI __device__ __forceinline__

// float -> bf16 bits, round-to-nearest-even
DEVI unsigned short f2b(float f) {
  union { float f; unsigned u; } v; v.f = f;
  return (unsigned short)((v.u + 0x7fffu + ((v.u >> 16) & 1u)) >> 16);
}

// async global->LDS, 16B per lane; LDS dest must be wave-uniform base + lane*16
#define GLD16(g, s) __builtin_amdgcn_global_load_lds( \
    (const __attribute__((address_space(1))) void*)(g), \
    (__attribute__((address_space(3))) void*)(s), 16, 0, 0)

// ---------------------------------------------------------------------------
// NT GEMM body: C[M][N] = A[M][K] * B[N][K]^T, bf16 in, f32 accum.
// 128x128 tile, BK=32, 4 waves, 16x16x32 MFMA.
// 2-phase double-buffered prefetch (T3-minimum): stage(next) issued BEFORE
// ds_read+MFMA(cur); single vmcnt(0)+barrier per K-step via __syncthreads.
// EPI: 0 = store bf16; 1 = store f32 * scale; 2 = store f32 + resid
template <int EPI>
DEVI void gemm_body(const unsigned short* __restrict__ A,
                    const unsigned short* __restrict__ B, void* __restrict__ Cv,
                    const float* __restrict__ resid, int bm, int bn, int K, int lda,
                    int ldb, int ldc, float scale, unsigned short* As,
                    unsigned short* Bs) {
  const int tid = threadIdx.x;
  const int wave = tid >> 6, lane = tid & 63;
  const int wm = wave >> 1, wn = wave & 1;

  f32x4 acc[4][4] = {};

  // staging geometry: each wave stages 32 rows (2x16) of each tile, 16B/lane/load
  const int r0 = wave * 32 + (lane >> 2);
  const int c0 = (lane & 3) * 8;
  const unsigned short* ga = A + (size_t)(bm * 128 + r0) * lda + c0;
  const unsigned short* gb = B + (size_t)(bn * 128 + r0) * ldb + c0;
  unsigned short* sa = As + wave * 1024 + lane * 8;
  unsigned short* sb = Bs + wave * 1024 + lane * 8;
  const size_t stepA16 = (size_t)16 * lda;
  const size_t stepB16 = (size_t)16 * ldb;

  const int rowa = wm * 64 + (lane & 15);
  const int rowb = wn * 64 + (lane & 15);
  const int kch = (lane >> 4) * 8;

  const int nK = K >> 5;

  auto stage = [&](int buf, int kt) {
    const unsigned short* gA = ga + kt * 32;
    const unsigned short* gB = gb + kt * 32;
    unsigned short* dA = sa + buf * 4096;
    unsigned short* dB = sb + buf * 4096;
    GLD16(gA, dA);
    GLD16(gA + stepA16, dA + 512);
    GLD16(gB, dB);
    GLD16(gB + stepB16, dB + 512);
  };

  stage(0, 0);
  __syncthreads();  // tile 0 resident
  int cur = 0;
  for (int kt = 0; kt < nK; ++kt) {
    if (kt + 1 < nK) stage(cur ^ 1, kt + 1);  // prefetch overlaps compute below
    const unsigned short* Ab = As + cur * 4096;
    const unsigned short* Bb = Bs + cur * 4096;
    short8 af[4], bq[4];
#pragma unroll
    for (int mi = 0; mi < 4; ++mi)
      af[mi] = *reinterpret_cast<const short8*>(&Ab[(rowa + mi * 16) * 32 + kch]);
#pragma unroll
    for (int ni = 0; ni < 4; ++ni)
      bq[ni] = *reinterpret_cast<const short8*>(&Bb[(rowb + ni * 16) * 32 + kch]);
#pragma unroll
    for (int mi = 0; mi < 4; ++mi)
#pragma unroll
      for (int ni = 0; ni < 4; ++ni)
        acc[mi][ni] = __builtin_amdgcn_mfma_f32_16x16x32_bf16(af[mi], bq[ni], acc[mi][ni], 0, 0, 0);
    __syncthreads();  // drains prefetch vmcnt + guards buf reuse
    cur ^= 1;
  }

  // epilogue: C/D layout col = lane&15, row = (lane>>4)*4 + reg  [m89-verified]
  const int cc = lane & 15, rr = (lane >> 4) * 4;
  const int rbase = bm * 128 + wm * 64, cbase = bn * 128 + wn * 64;
  if constexpr (EPI == 0) {
    unsigned short* C = (unsigned short*)Cv;
#pragma unroll
    for (int mi = 0; mi < 4; ++mi)
#pragma unroll
      for (int ni = 0; ni < 4; ++ni)
#pragma unroll
        for (int r = 0; r < 4; ++r)
          C[(size_t)(rbase + mi * 16 + rr + r) * ldc + (cbase + ni * 16 + cc)] =
              f2b(acc[mi][ni][r]);
  } else if constexpr (EPI == 1) {
    float* C = (float*)Cv;
#pragma unroll
    for (int mi = 0; mi < 4; ++mi)
#pragma unroll
      for (int ni = 0; ni < 4; ++ni)
#pragma unroll
        for (int r = 0; r < 4; ++r)
          C[(size_t)(rbase + mi * 16 + rr + r) * ldc + (cbase + ni * 16 + cc)] =
              acc[mi][ni][r] * scale;
  } else {
    float* C = (float*)Cv;
#pragma unroll
    for (int mi = 0; mi < 4; ++mi)
#pragma unroll
      for (int ni = 0; ni < 4; ++ni)
#pragma unroll
        for (int r = 0; r < 4; ++r) {
          const size_t idx = (size_t)(rbase + mi * 16 + rr + r) * ldc + (cbase + ni * 16 + cc);
          C[idx] = acc[mi][ni][r] + resid[idx];
        }
  }
}

// ---------------------------------------------------------------------------
// PREP (fused): pool(x1)->x1fT bf16 | transpose(x2)->x2fT bf16 | W->bf16
// 1-D grid: [0,3072) pool, [3072,6144) x2t, [6144,6720) wconv. block 256.
__global__ __launch_bounds__(256) void prep_kernel(
    const float* __restrict__ x1, const float* __restrict__ x2,
    const float* __restrict__ Wq, const float* __restrict__ Wk,
    const float* __restrict__ Wv, unsigned short* __restrict__ x1fT,
    unsigned short* __restrict__ x2fT, unsigned short* __restrict__ Wqb,
    unsigned short* __restrict__ Wkb, unsigned short* __restrict__ Wvb) {
  const int tid = threadIdx.x;
  __shared__ float tile[64][33];
  int id = blockIdx.x;
  if (id < 3072) {
    // ---- pool: 4x4 mean of x1[b][c][128][128] -> x1fT[(b*1024+n)][c] bf16
    const int c0 = (id % 12) * 64;
    const int ho = (id / 12) % 32;
    const int b = id / 384;
    const int ci = tid >> 5, wo = tid & 31;
#pragma unroll 2
    for (int cc = 0; cc < 8; ++cc) {
      const int c = c0 + cc * 8 + ci;
      const float* base = x1 + ((size_t)(b * 768 + c) * 128 + ho * 4) * 128 + wo * 4;
      float s = 0.f;
#pragma unroll
      for (int i = 0; i < 4; ++i) {
        f32x4 v = *reinterpret_cast<const f32x4*>(base + (size_t)i * 128);
        s += v[0] + v[1] + v[2] + v[3];
      }
      tile[cc * 8 + ci][wo] = s * 0.0625f;
    }
    __syncthreads();
    const int wo2 = tid >> 3, cg = tid & 7;
    uint4 pk;
    pk.x = (unsigned)f2b(tile[cg * 8 + 0][wo2]) | ((unsigned)f2b(tile[cg * 8 + 1][wo2]) << 16);
    pk.y = (unsigned)f2b(tile[cg * 8 + 2][wo2]) | ((unsigned)f2b(tile[cg * 8 + 3][wo2]) << 16);
    pk.z = (unsigned)f2b(tile[cg * 8 + 4][wo2]) | ((unsigned)f2b(tile[cg * 8 + 5][wo2]) << 16);
    pk.w = (unsigned)f2b(tile[cg * 8 + 6][wo2]) | ((unsigned)f2b(tile[cg * 8 + 7][wo2]) << 16);
    *reinterpret_cast<uint4*>(&x1fT[(size_t)(b * 1024 + ho * 32 + wo2) * 768 + c0 + cg * 8]) = pk;
  } else if (id < 6144) {
    // ---- x2 transpose: x2[b][c][n] -> x2fT[(b*1024+n)][c] bf16
    id -= 3072;
    const int ct = id % 12;
    const int nt = (id / 12) % 32;
    const int b = id / 384;
    {
      const int nl = tid & 31, cb = tid >> 5;
#pragma unroll
      for (int p = 0; p < 8; ++p) {
        const int cl = p * 8 + cb;
        tile[cl][nl] = x2[(size_t)(b * 768 + ct * 64 + cl) * 1024 + nt * 32 + nl];
      }
    }
    __syncthreads();
    {
      const int c2 = tid & 63, nb = tid >> 6;
#pragma unroll
      for (int p = 0; p < 8; ++p) {
        const int nl = p * 4 + nb;
        x2fT[(size_t)(b * 1024 + nt * 32 + nl) * 768 + ct * 64 + c2] = f2b(tile[c2][nl]);
      }
    }
  } else {
    // ---- weight convert f32->bf16, 16B stores
    const int i = (id - 6144) * 256 + tid;
    f32x4 a = reinterpret_cast<const f32x4*>(Wq)[i];
    f32x4 b = reinterpret_cast<const f32x4*>(Wk)[i];
    f32x4 c = reinterpret_cast<const f32x4*>(Wv)[i];
    uint2 oa, ob, oc;
    oa.x = (unsigned)f2b(a[0]) | ((unsigned)f2b(a[1]) << 16);
    oa.y = (unsigned)f2b(a[2]) | ((unsigned)f2b(a[3]) << 16);
    ob.x = (unsigned)f2b(b[0]) | ((unsigned)f2b(b[1]) << 16);
    ob.y = (unsigned)f2b(b[2]) | ((unsigned)f2b(b[3]) << 16);
    oc.x = (unsigned)f2b(c[0]) | ((unsigned)f2b(c[1]) << 16);
    oc.y = (unsigned)f2b(c[2]) | ((unsigned)f2b(c[3]) << 16);
    reinterpret_cast<uint2*>(Wqb)[i] = oa;
    reinterpret_cast<uint2*>(Wkb)[i] = ob;
    reinterpret_cast<uint2*>(Wvb)[i] = oc;
  }
}

// ---------------------------------------------------------------------------
// QKV (fused, one dispatch = 1152 blocks -> 4.5 blocks/CU latency hiding):
//  [0,384):   k  = Wk * x1f    -> kb  [768][8192]  (M=768,N=8192)
//  [384,768): q  = Wq * x2f    -> qb  [768][8192]
//  [768,1152):vT = x1fT * Wv^T -> vTb [8192][768]  (M=8192,N=768)
__global__ __launch_bounds__(256) void qkv_kernel(
    const unsigned short* __restrict__ Wkb, const unsigned short* __restrict__ Wqb,
    const unsigned short* __restrict__ Wvb, const unsigned short* __restrict__ x1fT,
    const unsigned short* __restrict__ x2fT, unsigned short* __restrict__ kb,
    unsigned short* __restrict__ qb, unsigned short* __restrict__ vTb) {
  __shared__ unsigned short As[2 * 4096];
  __shared__ unsigned short Bs[2 * 4096];
  int id = blockIdx.x;
  if (id < 384) {
    gemm_body<0>(Wkb, x1fT, kb, nullptr, id >> 6, id & 63, 768, 768, 768, 8192, 1.f, As, Bs);
  } else if (id < 768) {
    id -= 384;
    gemm_body<0>(Wqb, x2fT, qb, nullptr, id >> 6, id & 63, 768, 768, 768, 8192, 1.f, As, Bs);
  } else {
    id -= 768;
    gemm_body<0>(x1fT, Wvb, vTb, nullptr, id / 6, id % 6, 768, 768, 768, 768, 1.f, As, Bs);
  }
}

// attn[b] = q[b] * k[b]^T / 32   [768][768] f32, K=1024 (contract over n)
__global__ __launch_bounds__(256) void attn_kernel(const unsigned short* __restrict__ qb,
                                                   const unsigned short* __restrict__ kb,
                                                   float* __restrict__ attnf) {
  __shared__ unsigned short As[2 * 4096];
  __shared__ unsigned short Bs[2 * 4096];
  const int bz = blockIdx.z;
  gemm_body<1>(qb + bz * 1024, kb + bz * 1024, attnf + (size_t)bz * 589824, nullptr,
               blockIdx.y, blockIdx.x, 1024, 8192, 8192, 768, 1.f / 32.f, As, Bs);
}

// out[b] = attn[b] * v[b] + x2[b]   [768][1024] f32 -> d_out
__global__ __launch_bounds__(256) void out_kernel(const unsigned short* __restrict__ attnb,
                                                  const unsigned short* __restrict__ vTb,
                                                  float* __restrict__ out,
                                                  const float* __restrict__ x2) {
  __shared__ unsigned short As[2 * 4096];
  __shared__ unsigned short Bs[2 * 4096];
  const int bz = blockIdx.z;
  gemm_body<2>(attnb + (size_t)bz * 589824, vTb + (size_t)bz * 786432,
               out + (size_t)bz * 786432, x2 + (size_t)bz * 786432, blockIdx.y, blockIdx.x,
               768, 768, 768, 1024, 1.f, As, Bs);
}

// ---------------------------------------------------------------------------
// Row softmax: S [6144 rows][768] f32 -> P bf16, one wave per row
__global__ __launch_bounds__(256) void softmax_kernel(const float* __restrict__ S,
                                                      unsigned short* __restrict__ P) {
  const int row = blockIdx.x * 4 + (threadIdx.x >> 6);
  const int lane = threadIdx.x & 63;
  const float* r = S + (size_t)row * 768;
  f32x4 v[3];
  float mx = -1e30f;
#pragma unroll
  for (int i = 0; i < 3; ++i) {
    v[i] = *reinterpret_cast<const f32x4*>(r + (i * 64 + lane) * 4);
    mx = fmaxf(fmaxf(fmaxf(v[i][0], v[i][1]), fmaxf(v[i][2], v[i][3])), mx);
  }
#pragma unroll
  for (int off = 32; off > 0; off >>= 1) mx = fmaxf(mx, __shfl_xor(mx, off));
  float sum = 0.f;
#pragma unroll
  for (int i = 0; i < 3; ++i)
#pragma unroll
    for (int j = 0; j < 4; ++j) {
      v[i][j] = __expf(v[i][j] - mx);
      sum += v[i][j];
    }
#pragma unroll
  for (int off = 32; off > 0; off >>= 1) sum += __shfl_xor(sum, off);
  const float inv = 1.f / sum;
  unsigned short* p = P + (size_t)row * 768;
#pragma unroll
  for (int i = 0; i < 3; ++i) {
    uint2 o;
    o.x = (unsigned)f2b(v[i][0] * inv) | ((unsigned)f2b(v[i][1] * inv) << 16);
    o.y = (unsigned)f2b(v[i][2] * inv) | ((unsigned)f2b(v[i][3] * inv) << 16);
    *reinterpret_cast<uint2*>(p + (i * 64 + lane) * 4) = o;
  }
}

// ---------------------------------------------------------------------------
extern "C" void kernel_launch(void* const* d_in, const int* in_sizes, int n_in,
                              void* d_out, int out_size, void* d_ws, size_t ws_size,
                              hipStream_t stream) {
  const float* x1 = (const float*)d_in[0];  // [8][768][128][128]
  const float* x2 = (const float*)d_in[1];  // [8][768][32][32]
  const float* Wq = (const float*)d_in[2];  // [768][768]
  const float* Wk = (const float*)d_in[3];
  const float* Wv = (const float*)d_in[4];
  float* out = (float*)d_out;  // [8][768][32][32]

  char* ws = (char*)d_ws;
  size_t off = 0;
  auto alloc = [&](size_t bytes) {
    char* p = ws + off;
    off += (bytes + 255) & ~(size_t)255;
    return p;
  };
  unsigned short* x1fT = (unsigned short*)alloc((size_t)8192 * 768 * 2);  // [b*n][c1]
  unsigned short* x2fT = (unsigned short*)alloc((size_t)8192 * 768 * 2);  // [b*n][c2]
  unsigned short* Wqb = (unsigned short*)alloc((size_t)589824 * 2);
  unsigned short* Wkb = (unsigned short*)alloc((size_t)589824 * 2);
  unsigned short* Wvb = (unsigned short*)alloc((size_t)589824 * 2);
  unsigned short* qb = (unsigned short*)alloc((size_t)768 * 8192 * 2);   // [c2][b*n]
  unsigned short* kb = (unsigned short*)alloc((size_t)768 * 8192 * 2);   // [c1][b*n]
  unsigned short* vTb = (unsigned short*)alloc((size_t)8192 * 768 * 2);  // [b*n][c1]
  float* attnf = (float*)alloc((size_t)8 * 768 * 768 * 4);               // [b][c2][c1]
  unsigned short* attnb = x2fT;  // overlay: x2fT dead after q-GEMM

  // 1. prep: pool x1, transpose x2, convert weights (all independent, one dispatch)
  prep_kernel<<<dim3(6720), 256, 0, stream>>>(x1, x2, Wq, Wk, Wv, x1fT, x2fT, Wqb, Wkb, Wvb);
  // 2. q/k/vT GEMMs in one dispatch (1152 blocks)
  qkv_kernel<<<dim3(1152), 256, 0, stream>>>(Wkb, Wqb, Wvb, x1fT, x2fT, kb, qb, vTb);
  // 3. attn = q k^T / 32
  attn_kernel<<<dim3(6, 6, 8), 256, 0, stream>>>(qb, kb, attnf);
  // 4. softmax rows -> bf16 (into dead x2fT)
  softmax_kernel<<<dim3(1536), 256, 0, stream>>>(attnf, attnb);
  // 5. out = attn v + x2
  out_kernel<<<dim3(8, 6, 8), 256, 0, stream>>>(attnb, vTb, out, x2);
}

// Round 4
// 639.228 us; speedup vs baseline: 1.0815x; 1.0323x over previous
//
#include <hip/hip_runtime.h>
#include <stdint.h>

typedef __attribute__((ext_vector_type(8))) short short8;
typedef __attribute__((ext_vector_type(4))) float f32x4;

#define DEVI __device__ __forceinline__

// float -> bf16 bits, round-to-nearest-even
DEVI unsigned short f2b(float f) {
  union { float f; unsigned u; } v; v.f = f;
  return (unsigned short)((v.u + 0x7fffu + ((v.u >> 16) & 1u)) >> 16);
}

// async global->LDS, 16B per lane; LDS dest must be wave-uniform base + lane*16
#define GLD16(g, s) __builtin_amdgcn_global_load_lds( \
    (const __attribute__((address_space(1))) void*)(g), \
    (__attribute__((address_space(3))) void*)(s), 16, 0, 0)

// ---------------------------------------------------------------------------
// NT GEMM body: C[M][N] = A[M][K] * B[N][K]^T, bf16 in, f32 accum.
// 128x128 tile, BK=32, 4 waves, 16x16x32 MFMA.
// 4-buffer LDS ring, 2-deep prefetch, counted vmcnt (8 steady-state, never 0
// in main loop), ONE raw s_barrier per K-iter. Race safety: waves skew < 1
// barrier; at iter kt a wave stages buf (kt+2)&3 while the slowest wave holds
// live ds_reads only on bufs (kt-1)&3 / kt&3 -> disjoint mod 4.
// EPI: 0 = store bf16; 1 = store f32 * scale; 2 = store f32 + resid
template <int EPI>
DEVI void gemm_body(const unsigned short* __restrict__ A,
                    const unsigned short* __restrict__ B, void* __restrict__ Cv,
                    const float* __restrict__ resid, int bm, int bn, int K, int lda,
                    int ldb, int ldc, float scale, unsigned short* lds) {
  const int tid = threadIdx.x;
  const int wave = tid >> 6, lane = tid & 63;
  const int wm = wave >> 1, wn = wave & 1;

  f32x4 acc[4][4] = {};

  // staging geometry: each wave stages 32 rows (2x16) of each tile, 16B/lane/load
  const int r0 = wave * 32 + (lane >> 2);
  const int c0 = (lane & 3) * 8;
  const unsigned short* ga = A + (size_t)(bm * 128 + r0) * lda + c0;
  const unsigned short* gb = B + (size_t)(bn * 128 + r0) * ldb + c0;
  const size_t stepA16 = (size_t)16 * lda;
  const size_t stepB16 = (size_t)16 * ldb;
  unsigned short* sbase = lds + wave * 1024 + lane * 8;  // per-lane LDS stage addr

  const int rowa = wm * 64 + (lane & 15);
  const int rowb = wn * 64 + (lane & 15);
  const int kch = (lane >> 4) * 8;

  const int nK = K >> 5;

  auto stage = [&](int kt) {
    const int buf = kt & 3;
    const unsigned short* gA = ga + kt * 32;
    const unsigned short* gB = gb + kt * 32;
    unsigned short* dA = sbase + buf * 8192;
    unsigned short* dB = dA + 4096;
    GLD16(gA, dA);
    GLD16(gA + stepA16, dA + 512);
    GLD16(gB, dB);
    GLD16(gB + stepB16, dB + 512);
  };

  stage(0);
  if (nK > 1) stage(1);  // 8 loads in flight
  for (int kt = 0; kt < nK; ++kt) {
    if (kt + 2 < nK) {
      stage(kt + 2);  // 12 in flight; wait until only kt+1,kt+2 remain
      asm volatile("s_waitcnt vmcnt(8)" ::: "memory");
    } else if (kt + 1 < nK) {
      asm volatile("s_waitcnt vmcnt(4)" ::: "memory");
    } else {
      asm volatile("s_waitcnt vmcnt(0)" ::: "memory");
    }
    __builtin_amdgcn_s_barrier();  // tile kt resident for ALL waves
    asm volatile("" ::: "memory"); // fence: no ds_read hoist above barrier
    const unsigned short* Ab = lds + (kt & 3) * 8192;
    const unsigned short* Bb = Ab + 4096;
    short8 af[4], bq[4];
#pragma unroll
    for (int mi = 0; mi < 4; ++mi)
      af[mi] = *reinterpret_cast<const short8*>(&Ab[(rowa + mi * 16) * 32 + kch]);
#pragma unroll
    for (int ni = 0; ni < 4; ++ni)
      bq[ni] = *reinterpret_cast<const short8*>(&Bb[(rowb + ni * 16) * 32 + kch]);
#pragma unroll
    for (int mi = 0; mi < 4; ++mi)
#pragma unroll
      for (int ni = 0; ni < 4; ++ni)
        acc[mi][ni] = __builtin_amdgcn_mfma_f32_16x16x32_bf16(af[mi], bq[ni], acc[mi][ni], 0, 0, 0);
  }

  // epilogue: C/D layout col = lane&15, row = (lane>>4)*4 + reg  [m89-verified]
  const int cc = lane & 15, rr = (lane >> 4) * 4;
  const int rbase = bm * 128 + wm * 64, cbase = bn * 128 + wn * 64;
  if constexpr (EPI == 0) {
    unsigned short* C = (unsigned short*)Cv;
#pragma unroll
    for (int mi = 0; mi < 4; ++mi)
#pragma unroll
      for (int ni = 0; ni < 4; ++ni)
#pragma unroll
        for (int r = 0; r < 4; ++r)
          C[(size_t)(rbase + mi * 16 + rr + r) * ldc + (cbase + ni * 16 + cc)] =
              f2b(acc[mi][ni][r]);
  } else if constexpr (EPI == 1) {
    float* C = (float*)Cv;
#pragma unroll
    for (int mi = 0; mi < 4; ++mi)
#pragma unroll
      for (int ni = 0; ni < 4; ++ni)
#pragma unroll
        for (int r = 0; r < 4; ++r)
          C[(size_t)(rbase + mi * 16 + rr + r) * ldc + (cbase + ni * 16 + cc)] =
              acc[mi][ni][r] * scale;
  } else {
    float* C = (float*)Cv;
#pragma unroll
    for (int mi = 0; mi < 4; ++mi)
#pragma unroll
      for (int ni = 0; ni < 4; ++ni)
#pragma unroll
        for (int r = 0; r < 4; ++r) {
          const size_t idx = (size_t)(rbase + mi * 16 + rr + r) * ldc + (cbase + ni * 16 + cc);
          C[idx] = acc[mi][ni][r] + resid[idx];
        }
  }
}

// ---------------------------------------------------------------------------
// PREP (fused): pool(x1)->x1fT bf16 | transpose(x2)->x2fT bf16 | W->bf16
// 1-D grid: [0,3072) pool, [3072,6144) x2t, [6144,6720) wconv. block 256.
__global__ __launch_bounds__(256) void prep_kernel(
    const float* __restrict__ x1, const float* __restrict__ x2,
    const float* __restrict__ Wq, const float* __restrict__ Wk,
    const float* __restrict__ Wv, unsigned short* __restrict__ x1fT,
    unsigned short* __restrict__ x2fT, unsigned short* __restrict__ Wqb,
    unsigned short* __restrict__ Wkb, unsigned short* __restrict__ Wvb) {
  const int tid = threadIdx.x;
  __shared__ float tile[64][33];
  int id = blockIdx.x;
  if (id < 3072) {
    // ---- pool: 4x4 mean of x1[b][c][128][128] -> x1fT[(b*1024+n)][c] bf16
    const int c0 = (id % 12) * 64;
    const int ho = (id / 12) % 32;
    const int b = id / 384;
    const int ci = tid >> 5, wo = tid & 31;
#pragma unroll 2
    for (int cc = 0; cc < 8; ++cc) {
      const int c = c0 + cc * 8 + ci;
      const float* base = x1 + ((size_t)(b * 768 + c) * 128 + ho * 4) * 128 + wo * 4;
      float s = 0.f;
#pragma unroll
      for (int i = 0; i < 4; ++i) {
        f32x4 v = *reinterpret_cast<const f32x4*>(base + (size_t)i * 128);
        s += v[0] + v[1] + v[2] + v[3];
      }
      tile[cc * 8 + ci][wo] = s * 0.0625f;
    }
    __syncthreads();
    const int wo2 = tid >> 3, cg = tid & 7;
    uint4 pk;
    pk.x = (unsigned)f2b(tile[cg * 8 + 0][wo2]) | ((unsigned)f2b(tile[cg * 8 + 1][wo2]) << 16);
    pk.y = (unsigned)f2b(tile[cg * 8 + 2][wo2]) | ((unsigned)f2b(tile[cg * 8 + 3][wo2]) << 16);
    pk.z = (unsigned)f2b(tile[cg * 8 + 4][wo2]) | ((unsigned)f2b(tile[cg * 8 + 5][wo2]) << 16);
    pk.w = (unsigned)f2b(tile[cg * 8 + 6][wo2]) | ((unsigned)f2b(tile[cg * 8 + 7][wo2]) << 16);
    *reinterpret_cast<uint4*>(&x1fT[(size_t)(b * 1024 + ho * 32 + wo2) * 768 + c0 + cg * 8]) = pk;
  } else if (id < 6144) {
    // ---- x2 transpose: x2[b][c][n] -> x2fT[(b*1024+n)][c] bf16
    id -= 3072;
    const int ct = id % 12;
    const int nt = (id / 12) % 32;
    const int b = id / 384;
    {
      const int nl = tid & 31, cb = tid >> 5;
#pragma unroll
      for (int p = 0; p < 8; ++p) {
        const int cl = p * 8 + cb;
        tile[cl][nl] = x2[(size_t)(b * 768 + ct * 64 + cl) * 1024 + nt * 32 + nl];
      }
    }
    __syncthreads();
    {
      const int c2 = tid & 63, nb = tid >> 6;
#pragma unroll
      for (int p = 0; p < 8; ++p) {
        const int nl = p * 4 + nb;
        x2fT[(size_t)(b * 1024 + nt * 32 + nl) * 768 + ct * 64 + c2] = f2b(tile[c2][nl]);
      }
    }
  } else {
    // ---- weight convert f32->bf16, 16B stores
    const int i = (id - 6144) * 256 + tid;
    f32x4 a = reinterpret_cast<const f32x4*>(Wq)[i];
    f32x4 b = reinterpret_cast<const f32x4*>(Wk)[i];
    f32x4 c = reinterpret_cast<const f32x4*>(Wv)[i];
    uint2 oa, ob, oc;
    oa.x = (unsigned)f2b(a[0]) | ((unsigned)f2b(a[1]) << 16);
    oa.y = (unsigned)f2b(a[2]) | ((unsigned)f2b(a[3]) << 16);
    ob.x = (unsigned)f2b(b[0]) | ((unsigned)f2b(b[1]) << 16);
    ob.y = (unsigned)f2b(b[2]) | ((unsigned)f2b(b[3]) << 16);
    oc.x = (unsigned)f2b(c[0]) | ((unsigned)f2b(c[1]) << 16);
    oc.y = (unsigned)f2b(c[2]) | ((unsigned)f2b(c[3]) << 16);
    reinterpret_cast<uint2*>(Wqb)[i] = oa;
    reinterpret_cast<uint2*>(Wkb)[i] = ob;
    reinterpret_cast<uint2*>(Wvb)[i] = oc;
  }
}

// ---------------------------------------------------------------------------
// QKV (fused, one dispatch = 1152 blocks):
//  [0,384):   k  = Wk * x1f    -> kb  [768][8192]
//  [384,768): q  = Wq * x2f    -> qb  [768][8192]
//  [768,1152):vT = x1fT * Wv^T -> vTb [8192][768]
__global__ __launch_bounds__(256) void qkv_kernel(
    const unsigned short* __restrict__ Wkb, const unsigned short* __restrict__ Wqb,
    const unsigned short* __restrict__ Wvb, const unsigned short* __restrict__ x1fT,
    const unsigned short* __restrict__ x2fT, unsigned short* __restrict__ kb,
    unsigned short* __restrict__ qb, unsigned short* __restrict__ vTb) {
  __shared__ unsigned short lds[4 * 8192];  // 4 ring buffers x (A 8KB + B 8KB)
  int id = blockIdx.x;
  if (id < 384) {
    gemm_body<0>(Wkb, x1fT, kb, nullptr, id >> 6, id & 63, 768, 768, 768, 8192, 1.f, lds);
  } else if (id < 768) {
    id -= 384;
    gemm_body<0>(Wqb, x2fT, qb, nullptr, id >> 6, id & 63, 768, 768, 768, 8192, 1.f, lds);
  } else {
    id -= 768;
    gemm_body<0>(x1fT, Wvb, vTb, nullptr, id / 6, id % 6, 768, 768, 768, 768, 1.f, lds);
  }
}

// attn[b] = q[b] * k[b]^T / 32   [768][768] f32, K=1024 (contract over n)
__global__ __launch_bounds__(256) void attn_kernel(const unsigned short* __restrict__ qb,
                                                   const unsigned short* __restrict__ kb,
                                                   float* __restrict__ attnf) {
  __shared__ unsigned short lds[4 * 8192];
  const int bz = blockIdx.z;
  gemm_body<1>(qb + bz * 1024, kb + bz * 1024, attnf + (size_t)bz * 589824, nullptr,
               blockIdx.y, blockIdx.x, 1024, 8192, 8192, 768, 1.f / 32.f, lds);
}

// out[b] = attn[b] * v[b] + x2[b]   [768][1024] f32 -> d_out
__global__ __launch_bounds__(256) void out_kernel(const unsigned short* __restrict__ attnb,
                                                  const unsigned short* __restrict__ vTb,
                                                  float* __restrict__ out,
                                                  const float* __restrict__ x2) {
  __shared__ unsigned short lds[4 * 8192];
  const int bz = blockIdx.z;
  gemm_body<2>(attnb + (size_t)bz * 589824, vTb + (size_t)bz * 786432,
               out + (size_t)bz * 786432, x2 + (size_t)bz * 786432, blockIdx.y, blockIdx.x,
               768, 768, 768, 1024, 1.f, lds);
}

// ---------------------------------------------------------------------------
// Row softmax: S [6144 rows][768] f32 -> P bf16, one wave per row
__global__ __launch_bounds__(256) void softmax_kernel(const float* __restrict__ S,
                                                      unsigned short* __restrict__ P) {
  const int row = blockIdx.x * 4 + (threadIdx.x >> 6);
  const int lane = threadIdx.x & 63;
  const float* r = S + (size_t)row * 768;
  f32x4 v[3];
  float mx = -1e30f;
#pragma unroll
  for (int i = 0; i < 3; ++i) {
    v[i] = *reinterpret_cast<const f32x4*>(r + (i * 64 + lane) * 4);
    mx = fmaxf(fmaxf(fmaxf(v[i][0], v[i][1]), fmaxf(v[i][2], v[i][3])), mx);
  }
#pragma unroll
  for (int off = 32; off > 0; off >>= 1) mx = fmaxf(mx, __shfl_xor(mx, off));
  float sum = 0.f;
#pragma unroll
  for (int i = 0; i < 3; ++i)
#pragma unroll
    for (int j = 0; j < 4; ++j) {
      v[i][j] = __expf(v[i][j] - mx);
      sum += v[i][j];
    }
#pragma unroll
  for (int off = 32; off > 0; off >>= 1) sum += __shfl_xor(sum, off);
  const float inv = 1.f / sum;
  unsigned short* p = P + (size_t)row * 768;
#pragma unroll
  for (int i = 0; i < 3; ++i) {
    uint2 o;
    o.x = (unsigned)f2b(v[i][0] * inv) | ((unsigned)f2b(v[i][1] * inv) << 16);
    o.y = (unsigned)f2b(v[i][2] * inv) | ((unsigned)f2b(v[i][3] * inv) << 16);
    *reinterpret_cast<uint2*>(p + (i * 64 + lane) * 4) = o;
  }
}

// ---------------------------------------------------------------------------
extern "C" void kernel_launch(void* const* d_in, const int* in_sizes, int n_in,
                              void* d_out, int out_size, void* d_ws, size_t ws_size,
                              hipStream_t stream) {
  const float* x1 = (const float*)d_in[0];  // [8][768][128][128]
  const float* x2 = (const float*)d_in[1];  // [8][768][32][32]
  const float* Wq = (const float*)d_in[2];  // [768][768]
  const float* Wk = (const float*)d_in[3];
  const float* Wv = (const float*)d_in[4];
  float* out = (float*)d_out;  // [8][768][32][32]

  char* ws = (char*)d_ws;
  size_t off = 0;
  auto alloc = [&](size_t bytes) {
    char* p = ws + off;
    off += (bytes + 255) & ~(size_t)255;
    return p;
  };
  unsigned short* x1fT = (unsigned short*)alloc((size_t)8192 * 768 * 2);  // [b*n][c1]
  unsigned short* x2fT = (unsigned short*)alloc((size_t)8192 * 768 * 2);  // [b*n][c2]
  unsigned short* Wqb = (unsigned short*)alloc((size_t)589824 * 2);
  unsigned short* Wkb = (unsigned short*)alloc((size_t)589824 * 2);
  unsigned short* Wvb = (unsigned short*)alloc((size_t)589824 * 2);
  unsigned short* qb = (unsigned short*)alloc((size_t)768 * 8192 * 2);   // [c2][b*n]
  unsigned short* kb = (unsigned short*)alloc((size_t)768 * 8192 * 2);   // [c1][b*n]
  unsigned short* vTb = (unsigned short*)alloc((size_t)8192 * 768 * 2);  // [b*n][c1]
  float* attnf = (float*)alloc((size_t)8 * 768 * 768 * 4);               // [b][c2][c1]
  unsigned short* attnb = x2fT;  // overlay: x2fT dead after q-GEMM

  // 1. prep: pool x1, transpose x2, convert weights (all independent, one dispatch)
  prep_kernel<<<dim3(6720), 256, 0, stream>>>(x1, x2, Wq, Wk, Wv, x1fT, x2fT, Wqb, Wkb, Wvb);
  // 2. q/k/vT GEMMs in one dispatch (1152 blocks)
  qkv_kernel<<<dim3(1152), 256, 0, stream>>>(Wkb, Wqb, Wvb, x1fT, x2fT, kb, qb, vTb);
  // 3. attn = q k^T / 32
  attn_kernel<<<dim3(6, 6, 8), 256, 0, stream>>>(qb, kb, attnf);
  // 4. softmax rows -> bf16 (into dead x2fT)
  softmax_kernel<<<dim3(1536), 256, 0, stream>>>(attnf, attnb);
  // 5. out = attn v + x2
  out_kernel<<<dim3(8, 6, 8), 256, 0, stream>>>(attnb, vTb, out, x2);
}

// Round 6
// 638.720 us; speedup vs baseline: 1.0824x; 1.0008x over previous
//
#include <hip/hip_runtime.h>
#include <stdint.h>

typedef __attribute__((ext_vector_type(8))) short short8;
typedef __attribute__((ext_vector_type(4))) float f32x4;

#define DEVI __device__ __forceinline__

// float -> bf16 bits, round-to-nearest-even
DEVI unsigned short f2b(float f) {
  union { float f; unsigned u; } v; v.f = f;
  return (unsigned short)((v.u + 0x7fffu + ((v.u >> 16) & 1u)) >> 16);
}

// async global->LDS, 16B per lane; LDS dest must be wave-uniform base + lane*16
#define GLD16(g, s) __builtin_amdgcn_global_load_lds( \
    (const __attribute__((address_space(1))) void*)(g), \
    (__attribute__((address_space(3))) void*)(s), 16, 0, 0)

// ---------------------------------------------------------------------------
// NT GEMM body: C[M][N] = A[M][K] * B[N][K]^T, bf16 in, f32 accum.
// 128x128 tile, BK=32, 4 waves, 16x16x32 MFMA.
// 3-buffer LDS ring (48 KB -> 3 blocks/CU), 2-deep prefetch, counted vmcnt
// (4 steady-state), ONE raw s_barrier per K-iter, stage issued AFTER barrier.
// Ring safety: at barrier kt every wave has consumed its ds_reads of buf
// (kt-1)%3 (the consuming MFMAs precede the barrier in program order, and the
// compiler's lgkmcnt waits precede those) -> staging (kt+2)%3 == (kt-1)%3 is
// race-free. vmcnt(4) at iter kt waits for stage(kt)'s 4 loads, leaving
// stage(kt+1) in flight across the barrier.
// EPI: 0 = store bf16; 1 = store f32 * scale; 2 = store f32 + resid
template <int EPI>
DEVI void gemm_body(const unsigned short* __restrict__ A,
                    const unsigned short* __restrict__ B, void* __restrict__ Cv,
                    const float* __restrict__ resid, int bm, int bn, int K, int lda,
                    int ldb, int ldc, float scale, unsigned short* lds) {
  const int tid = threadIdx.x;
  const int wave = tid >> 6, lane = tid & 63;
  const int wm = wave >> 1, wn = wave & 1;

  f32x4 acc[4][4] = {};

  // staging geometry: each wave stages 32 rows (2x16) of each tile, 16B/lane/load
  const int r0 = wave * 32 + (lane >> 2);
  const int c0 = (lane & 3) * 8;
  const unsigned short* ga = A + (size_t)(bm * 128 + r0) * lda + c0;
  const unsigned short* gb = B + (size_t)(bn * 128 + r0) * ldb + c0;
  const size_t stepA16 = (size_t)16 * lda;
  const size_t stepB16 = (size_t)16 * ldb;
  unsigned short* sbase = lds + wave * 1024 + lane * 8;  // per-lane LDS stage addr

  const int rowa = wm * 64 + (lane & 15);
  const int rowb = wn * 64 + (lane & 15);
  const int kch = (lane >> 4) * 8;

  const int nK = K >> 5;

  auto stage = [&](int kt, int buf) {
    const unsigned short* gA = ga + kt * 32;
    const unsigned short* gB = gb + kt * 32;
    unsigned short* dA = sbase + buf * 8192;
    unsigned short* dB = dA + 4096;
    GLD16(gA, dA);
    GLD16(gA + stepA16, dA + 512);
    GLD16(gB, dB);
    GLD16(gB + stepB16, dB + 512);
  };

  stage(0, 0);
  stage(1, 1);  // 8 loads in flight
  int bcur = 0;
  for (int kt = 0; kt < nK; ++kt) {
    if (kt + 1 < nK) {
      asm volatile("s_waitcnt vmcnt(4)" ::: "memory");  // stage(kt) resident
    } else {
      asm volatile("s_waitcnt vmcnt(0)" ::: "memory");
    }
    __builtin_amdgcn_s_barrier();  // tile kt resident for ALL waves
    asm volatile("" ::: "memory"); // fence: no ds_read hoist above barrier
    if (kt + 2 < nK) {
      int bpre = bcur + 2; if (bpre >= 3) bpre -= 3;
      stage(kt + 2, bpre);  // overwrites buf (kt-1)%3: consumed by all waves
    }
    const unsigned short* Ab = lds + bcur * 8192;
    const unsigned short* Bb = Ab + 4096;
    short8 af[4], bq[4];
#pragma unroll
    for (int mi = 0; mi < 4; ++mi)
      af[mi] = *reinterpret_cast<const short8*>(&Ab[(rowa + mi * 16) * 32 + kch]);
#pragma unroll
    for (int ni = 0; ni < 4; ++ni)
      bq[ni] = *reinterpret_cast<const short8*>(&Bb[(rowb + ni * 16) * 32 + kch]);
#pragma unroll
    for (int mi = 0; mi < 4; ++mi)
#pragma unroll
      for (int ni = 0; ni < 4; ++ni)
        acc[mi][ni] = __builtin_amdgcn_mfma_f32_16x16x32_bf16(af[mi], bq[ni], acc[mi][ni], 0, 0, 0);
    ++bcur; if (bcur == 3) bcur = 0;
  }

  // epilogue: C/D layout col = lane&15, row = (lane>>4)*4 + reg  [m89-verified]
  const int cc = lane & 15, rr = (lane >> 4) * 4;
  const int rbase = bm * 128 + wm * 64, cbase = bn * 128 + wn * 64;
  if constexpr (EPI == 0) {
    unsigned short* C = (unsigned short*)Cv;
#pragma unroll
    for (int mi = 0; mi < 4; ++mi)
#pragma unroll
      for (int ni = 0; ni < 4; ++ni)
#pragma unroll
        for (int r = 0; r < 4; ++r)
          C[(size_t)(rbase + mi * 16 + rr + r) * ldc + (cbase + ni * 16 + cc)] =
              f2b(acc[mi][ni][r]);
  } else if constexpr (EPI == 1) {
    float* C = (float*)Cv;
#pragma unroll
    for (int mi = 0; mi < 4; ++mi)
#pragma unroll
      for (int ni = 0; ni < 4; ++ni)
#pragma unroll
        for (int r = 0; r < 4; ++r)
          C[(size_t)(rbase + mi * 16 + rr + r) * ldc + (cbase + ni * 16 + cc)] =
              acc[mi][ni][r] * scale;
  } else {
    float* C = (float*)Cv;
#pragma unroll
    for (int mi = 0; mi < 4; ++mi)
#pragma unroll
      for (int ni = 0; ni < 4; ++ni)
#pragma unroll
        for (int r = 0; r < 4; ++r) {
          const size_t idx = (size_t)(rbase + mi * 16 + rr + r) * ldc + (cbase + ni * 16 + cc);
          C[idx] = acc[mi][ni][r] + resid[idx];
        }
  }
}

// ---------------------------------------------------------------------------
// PREP (fused): pool(x1)->x1fT bf16 | transpose(x2)->x2fT bf16 | W->bf16
// 1-D grid: [0,3072) pool, [3072,6144) x2t, [6144,6720) wconv. block 256.
__global__ __launch_bounds__(256) void prep_kernel(
    const float* __restrict__ x1, const float* __restrict__ x2,
    const float* __restrict__ Wq, const float* __restrict__ Wk,
    const float* __restrict__ Wv, unsigned short* __restrict__ x1fT,
    unsigned short* __restrict__ x2fT, unsigned short* __restrict__ Wqb,
    unsigned short* __restrict__ Wkb, unsigned short* __restrict__ Wvb) {
  const int tid = threadIdx.x;
  __shared__ float tile[64][33];
  int id = blockIdx.x;
  if (id < 3072) {
    // ---- pool: 4x4 mean of x1[b][c][128][128] -> x1fT[(b*1024+n)][c] bf16
    const int c0 = (id % 12) * 64;
    const int ho = (id / 12) % 32;
    const int b = id / 384;
    const int ci = tid >> 5, wo = tid & 31;
#pragma unroll 2
    for (int cc = 0; cc < 8; ++cc) {
      const int c = c0 + cc * 8 + ci;
      const float* base = x1 + ((size_t)(b * 768 + c) * 128 + ho * 4) * 128 + wo * 4;
      float s = 0.f;
#pragma unroll
      for (int i = 0; i < 4; ++i) {
        f32x4 v = *reinterpret_cast<const f32x4*>(base + (size_t)i * 128);
        s += v[0] + v[1] + v[2] + v[3];
      }
      tile[cc * 8 + ci][wo] = s * 0.0625f;
    }
    __syncthreads();
    const int wo2 = tid >> 3, cg = tid & 7;
    uint4 pk;
    pk.x = (unsigned)f2b(tile[cg * 8 + 0][wo2]) | ((unsigned)f2b(tile[cg * 8 + 1][wo2]) << 16);
    pk.y = (unsigned)f2b(tile[cg * 8 + 2][wo2]) | ((unsigned)f2b(tile[cg * 8 + 3][wo2]) << 16);
    pk.z = (unsigned)f2b(tile[cg * 8 + 4][wo2]) | ((unsigned)f2b(tile[cg * 8 + 5][wo2]) << 16);
    pk.w = (unsigned)f2b(tile[cg * 8 + 6][wo2]) | ((unsigned)f2b(tile[cg * 8 + 7][wo2]) << 16);
    *reinterpret_cast<uint4*>(&x1fT[(size_t)(b * 1024 + ho * 32 + wo2) * 768 + c0 + cg * 8]) = pk;
  } else if (id < 6144) {
    // ---- x2 transpose: x2[b][c][n] -> x2fT[(b*1024+n)][c] bf16
    id -= 3072;
    const int ct = id % 12;
    const int nt = (id / 12) % 32;
    const int b = id / 384;
    {
      const int nl = tid & 31, cb = tid >> 5;
#pragma unroll
      for (int p = 0; p < 8; ++p) {
        const int cl = p * 8 + cb;
        tile[cl][nl] = x2[(size_t)(b * 768 + ct * 64 + cl) * 1024 + nt * 32 + nl];
      }
    }
    __syncthreads();
    {
      const int c2 = tid & 63, nb = tid >> 6;
#pragma unroll
      for (int p = 0; p < 8; ++p) {
        const int nl = p * 4 + nb;
        x2fT[(size_t)(b * 1024 + nt * 32 + nl) * 768 + ct * 64 + c2] = f2b(tile[c2][nl]);
      }
    }
  } else {
    // ---- weight convert f32->bf16, 16B stores
    const int i = (id - 6144) * 256 + tid;
    f32x4 a = reinterpret_cast<const f32x4*>(Wq)[i];
    f32x4 b = reinterpret_cast<const f32x4*>(Wk)[i];
    f32x4 c = reinterpret_cast<const f32x4*>(Wv)[i];
    uint2 oa, ob, oc;
    oa.x = (unsigned)f2b(a[0]) | ((unsigned)f2b(a[1]) << 16);
    oa.y = (unsigned)f2b(a[2]) | ((unsigned)f2b(a[3]) << 16);
    ob.x = (unsigned)f2b(b[0]) | ((unsigned)f2b(b[1]) << 16);
    ob.y = (unsigned)f2b(b[2]) | ((unsigned)f2b(b[3]) << 16);
    oc.x = (unsigned)f2b(c[0]) | ((unsigned)f2b(c[1]) << 16);
    oc.y = (unsigned)f2b(c[2]) | ((unsigned)f2b(c[3]) << 16);
    reinterpret_cast<uint2*>(Wqb)[i] = oa;
    reinterpret_cast<uint2*>(Wkb)[i] = ob;
    reinterpret_cast<uint2*>(Wvb)[i] = oc;
  }
}

// ---------------------------------------------------------------------------
// QKV (fused, one dispatch = 1152 blocks, 3 blocks/CU):
//  [0,384):   k  = Wk * x1f    -> kb  [768][8192]
//  [384,768): q  = Wq * x2f    -> qb  [768][8192]
//  [768,1152):vT = x1fT * Wv^T -> vTb [8192][768]
__global__ __launch_bounds__(256, 3) void qkv_kernel(
    const unsigned short* __restrict__ Wkb, const unsigned short* __restrict__ Wqb,
    const unsigned short* __restrict__ Wvb, const unsigned short* __restrict__ x1fT,
    const unsigned short* __restrict__ x2fT, unsigned short* __restrict__ kb,
    unsigned short* __restrict__ qb, unsigned short* __restrict__ vTb) {
  __shared__ unsigned short lds[3 * 8192];  // 3 ring buffers x (A 8KB + B 8KB)
  int id = blockIdx.x;
  if (id < 384) {
    gemm_body<0>(Wkb, x1fT, kb, nullptr, id >> 6, id & 63, 768, 768, 768, 8192, 1.f, lds);
  } else if (id < 768) {
    id -= 384;
    gemm_body<0>(Wqb, x2fT, qb, nullptr, id >> 6, id & 63, 768, 768, 768, 8192, 1.f, lds);
  } else {
    id -= 768;
    gemm_body<0>(x1fT, Wvb, vTb, nullptr, id / 6, id % 6, 768, 768, 768, 768, 1.f, lds);
  }
}

// attn partials: p[kh][b] = q[b][:, kh*512:+512] * k[b][:, kh*512:+512]^T / 32
// grid (6,6,16): z = kh*8 + b. Split-K=2 -> 576 blocks, 16 iters each.
__global__ __launch_bounds__(256, 3) void attn_kernel(const unsigned short* __restrict__ qb,
                                                      const unsigned short* __restrict__ kb,
                                                      float* __restrict__ attnp) {
  __shared__ unsigned short lds[3 * 8192];
  const int z = blockIdx.z;
  const int b = z & 7, kh = z >> 3;
  gemm_body<1>(qb + b * 1024 + kh * 512, kb + b * 1024 + kh * 512,
               attnp + (size_t)z * 589824, nullptr, blockIdx.y, blockIdx.x, 512, 8192,
               8192, 768, 1.f / 32.f, lds);
}

// out[b] = attn[b] * v[b] + x2[b]   [768][1024] f32 -> d_out
__global__ __launch_bounds__(256, 3) void out_kernel(const unsigned short* __restrict__ attnb,
                                                     const unsigned short* __restrict__ vTb,
                                                     float* __restrict__ out,
                                                     const float* __restrict__ x2) {
  __shared__ unsigned short lds[3 * 8192];
  const int bz = blockIdx.z;
  gemm_body<2>(attnb + (size_t)bz * 589824, vTb + (size_t)bz * 786432,
               out + (size_t)bz * 786432, x2 + (size_t)bz * 786432, blockIdx.y, blockIdx.x,
               768, 768, 768, 1024, 1.f, lds);
}

// ---------------------------------------------------------------------------
// Row softmax over summed split-K partials: S = p0 + p1 (already scaled),
// [6144 rows][768] f32 -> P bf16, one wave per row.
__global__ __launch_bounds__(256) void softmax_kernel(const float* __restrict__ S,
                                                      unsigned short* __restrict__ P) {
  const int row = blockIdx.x * 4 + (threadIdx.x >> 6);
  const int lane = threadIdx.x & 63;
  const float* r0 = S + (size_t)row * 768;
  const float* r1 = r0 + (size_t)8 * 589824;  // second K-half partial
  f32x4 v[3];
  float mx = -1e30f;
#pragma unroll
  for (int i = 0; i < 3; ++i) {
    f32x4 a = *reinterpret_cast<const f32x4*>(r0 + (i * 64 + lane) * 4);
    f32x4 b = *reinterpret_cast<const f32x4*>(r1 + (i * 64 + lane) * 4);
    v[i][0] = a[0] + b[0]; v[i][1] = a[1] + b[1];
    v[i][2] = a[2] + b[2]; v[i][3] = a[3] + b[3];
    mx = fmaxf(fmaxf(fmaxf(v[i][0], v[i][1]), fmaxf(v[i][2], v[i][3])), mx);
  }
#pragma unroll
  for (int off = 32; off > 0; off >>= 1) mx = fmaxf(mx, __shfl_xor(mx, off));
  float sum = 0.f;
#pragma unroll
  for (int i = 0; i < 3; ++i)
#pragma unroll
    for (int j = 0; j < 4; ++j) {
      v[i][j] = __expf(v[i][j] - mx);
      sum += v[i][j];
    }
#pragma unroll
  for (int off = 32; off > 0; off >>= 1) sum += __shfl_xor(sum, off);
  const float inv = 1.f / sum;
  unsigned short* p = P + (size_t)row * 768;
#pragma unroll
  for (int i = 0; i < 3; ++i) {
    uint2 o;
    o.x = (unsigned)f2b(v[i][0] * inv) | ((unsigned)f2b(v[i][1] * inv) << 16);
    o.y = (unsigned)f2b(v[i][2] * inv) | ((unsigned)f2b(v[i][3] * inv) << 16);
    *reinterpret_cast<uint2*>(p + (i * 64 + lane) * 4) = o;
  }
}

// ---------------------------------------------------------------------------
extern "C" void kernel_launch(void* const* d_in, const int* in_sizes, int n_in,
                              void* d_out, int out_size, void* d_ws, size_t ws_size,
                              hipStream_t stream) {
  const float* x1 = (const float*)d_in[0];  // [8][768][128][128]
  const float* x2 = (const float*)d_in[1];  // [8][768][32][32]
  const float* Wq = (const float*)d_in[2];  // [768][768]
  const float* Wk = (const float*)d_in[3];
  const float* Wv = (const float*)d_in[4];
  float* out = (float*)d_out;  // [8][768][32][32]

  char* ws = (char*)d_ws;
  size_t off = 0;
  auto alloc = [&](size_t bytes) {
    char* p = ws + off;
    off += (bytes + 255) & ~(size_t)255;
    return p;
  };
  unsigned short* x1fT = (unsigned short*)alloc((size_t)8192 * 768 * 2);  // [b*n][c1]
  unsigned short* x2fT = (unsigned short*)alloc((size_t)8192 * 768 * 2);  // [b*n][c2]
  unsigned short* Wqb = (unsigned short*)alloc((size_t)589824 * 2);
  unsigned short* Wkb = (unsigned short*)alloc((size_t)589824 * 2);
  unsigned short* Wvb = (unsigned short*)alloc((size_t)589824 * 2);
  unsigned short* qb = (unsigned short*)alloc((size_t)768 * 8192 * 2);   // [c2][b*n]
  unsigned short* kb = (unsigned short*)alloc((size_t)768 * 8192 * 2);   // [c1][b*n]
  unsigned short* vTb = (unsigned short*)alloc((size_t)8192 * 768 * 2);  // [b*n][c1]
  float* attnp = (float*)alloc((size_t)2 * 8 * 768 * 768 * 4);           // [kh][b][c2][c1]
  unsigned short* attnb = x2fT;  // overlay: x2fT dead after q-GEMM

  // 1. prep: pool x1, transpose x2, convert weights (all independent, one dispatch)
  prep_kernel<<<dim3(6720), 256, 0, stream>>>(x1, x2, Wq, Wk, Wv, x1fT, x2fT, Wqb, Wkb, Wvb);
  // 2. q/k/vT GEMMs in one dispatch (1152 blocks, 3/CU)
  qkv_kernel<<<dim3(1152), 256, 0, stream>>>(Wkb, Wqb, Wvb, x1fT, x2fT, kb, qb, vTb);
  // 3. attn partials (split-K=2, 576 blocks)
  attn_kernel<<<dim3(6, 6, 16), 256, 0, stream>>>(qb, kb, attnp);
  // 4. softmax over summed partials -> bf16 (into dead x2fT)
  softmax_kernel<<<dim3(1536), 256, 0, stream>>>(attnp, attnb);
  // 5. out = attn v + x2
  out_kernel<<<dim3(8, 6, 8), 256, 0, stream>>>(attnb, vTb, out, x2);
}

// Round 7
// 633.931 us; speedup vs baseline: 1.0906x; 1.0076x over previous
//
#include <hip/hip_runtime.h>
#include <stdint.h>

typedef __attribute__((ext_vector_type(8))) short short8;
typedef __attribute__((ext_vector_type(4))) float f32x4;

#define DEVI __device__ __forceinline__

// float -> bf16 bits, round-to-nearest-even
DEVI unsigned short f2b(float f) {
  union { float f; unsigned u; } v; v.f = f;
  return (unsigned short)((v.u + 0x7fffu + ((v.u >> 16) & 1u)) >> 16);
}

// async global->LDS, 16B per lane; LDS dest must be wave-uniform base + lane*16
#define GLD16(g, s) __builtin_amdgcn_global_load_lds( \
    (const __attribute__((address_space(1))) void*)(g), \
    (__attribute__((address_space(3))) void*)(s), 16, 0, 0)

// ---------------------------------------------------------------------------
// NT GEMM body: C[M][N] = A[M][K] * B[N][K]^T, bf16 in, f32 accum.
// 128x128 tile, BK=32, 4 waves, 16x16x32 MFMA.
// 3-buffer LDS ring (48 KB -> 3 blocks/CU), 2-deep prefetch, counted vmcnt,
// ONE raw s_barrier per K-iter, stage issued AFTER barrier.
//
// LDS BANK-CONFLICT SWIZZLE (T2, both-sides-or-neither):
// Linear [row][32bf16] layout has ds_read_b128 at stride 64B -> banks
// alternate {0,16} within a 16-lane quarter = 8-way conflict (~2.9x, m136).
// Fix: LDS 16B-slot (row, s) holds global k-chunk (s ^ ((row>>1)&3)).
//  - staging: global source col permuted per lane: slot = (lane&3)^((lane>>3)&3)
//    (row_local = lane>>2; (row>>1)&3 == (lane>>3)&3 for BOTH 16-row halves
//    and all waves since those offsets are multiples of 32 rows / 16 rows).
//  - read: kch = ((lane>>4) ^ ((lane>>1)&3))*8; rowa/rowb terms (wm*64, mi*16)
//    are multiples of 4 rows so (row>>1)&3 == (lane>>1)&3.
// Post-swizzle: 8 lanes per bank-quad uniformly = wave64 floor (2/bank, free).
//
// EPI: 0 = store bf16; 1 = store f32 * scale; 2 = store f32 + resid
template <int EPI>
DEVI void gemm_body(const unsigned short* __restrict__ A,
                    const unsigned short* __restrict__ B, void* __restrict__ Cv,
                    const float* __restrict__ resid, int bm, int bn, int K, int lda,
                    int ldb, int ldc, float scale, unsigned short* lds) {
  const int tid = threadIdx.x;
  const int wave = tid >> 6, lane = tid & 63;
  const int wm = wave >> 1, wn = wave & 1;

  f32x4 acc[4][4] = {};

  // staging geometry: each wave stages 32 rows (2x16) of each tile, 16B/lane/load
  const int r0 = wave * 32 + (lane >> 2);
  const int c0 = (((lane & 3) ^ ((lane >> 3) & 3)) * 8);  // swizzled source slot
  const unsigned short* ga = A + (size_t)(bm * 128 + r0) * lda + c0;
  const unsigned short* gb = B + (size_t)(bn * 128 + r0) * ldb + c0;
  const size_t stepA16 = (size_t)16 * lda;
  const size_t stepB16 = (size_t)16 * ldb;
  unsigned short* sbase = lds + wave * 1024 + lane * 8;  // per-lane LDS stage addr

  const int rowa = wm * 64 + (lane & 15);
  const int rowb = wn * 64 + (lane & 15);
  const int kch = (((lane >> 4) ^ ((lane >> 1) & 3)) * 8);  // swizzled read slot

  const int nK = K >> 5;

  auto stage = [&](int kt, int buf) {
    const unsigned short* gA = ga + kt * 32;
    const unsigned short* gB = gb + kt * 32;
    unsigned short* dA = sbase + buf * 8192;
    unsigned short* dB = dA + 4096;
    GLD16(gA, dA);
    GLD16(gA + stepA16, dA + 512);
    GLD16(gB, dB);
    GLD16(gB + stepB16, dB + 512);
  };

  stage(0, 0);
  stage(1, 1);  // 8 loads in flight
  int bcur = 0;
  for (int kt = 0; kt < nK; ++kt) {
    if (kt + 1 < nK) {
      asm volatile("s_waitcnt vmcnt(4)" ::: "memory");  // stage(kt) resident
    } else {
      asm volatile("s_waitcnt vmcnt(0)" ::: "memory");
    }
    __builtin_amdgcn_s_barrier();  // tile kt resident for ALL waves
    asm volatile("" ::: "memory"); // fence: no ds_read hoist above barrier
    if (kt + 2 < nK) {
      int bpre = bcur + 2; if (bpre >= 3) bpre -= 3;
      stage(kt + 2, bpre);  // overwrites buf (kt-1)%3: consumed by all waves
    }
    const unsigned short* Ab = lds + bcur * 8192;
    const unsigned short* Bb = Ab + 4096;
    short8 af[4], bq[4];
#pragma unroll
    for (int mi = 0; mi < 4; ++mi)
      af[mi] = *reinterpret_cast<const short8*>(&Ab[(rowa + mi * 16) * 32 + kch]);
#pragma unroll
    for (int ni = 0; ni < 4; ++ni)
      bq[ni] = *reinterpret_cast<const short8*>(&Bb[(rowb + ni * 16) * 32 + kch]);
#pragma unroll
    for (int mi = 0; mi < 4; ++mi)
#pragma unroll
      for (int ni = 0; ni < 4; ++ni)
        acc[mi][ni] = __builtin_amdgcn_mfma_f32_16x16x32_bf16(af[mi], bq[ni], acc[mi][ni], 0, 0, 0);
    ++bcur; if (bcur == 3) bcur = 0;
  }

  // epilogue: C/D layout col = lane&15, row = (lane>>4)*4 + reg  [m89-verified]
  const int cc = lane & 15, rr = (lane >> 4) * 4;
  const int rbase = bm * 128 + wm * 64, cbase = bn * 128 + wn * 64;
  if constexpr (EPI == 0) {
    unsigned short* C = (unsigned short*)Cv;
#pragma unroll
    for (int mi = 0; mi < 4; ++mi)
#pragma unroll
      for (int ni = 0; ni < 4; ++ni)
#pragma unroll
        for (int r = 0; r < 4; ++r)
          C[(size_t)(rbase + mi * 16 + rr + r) * ldc + (cbase + ni * 16 + cc)] =
              f2b(acc[mi][ni][r]);
  } else if constexpr (EPI == 1) {
    float* C = (float*)Cv;
#pragma unroll
    for (int mi = 0; mi < 4; ++mi)
#pragma unroll
      for (int ni = 0; ni < 4; ++ni)
#pragma unroll
        for (int r = 0; r < 4; ++r)
          C[(size_t)(rbase + mi * 16 + rr + r) * ldc + (cbase + ni * 16 + cc)] =
              acc[mi][ni][r] * scale;
  } else {
    float* C = (float*)Cv;
#pragma unroll
    for (int mi = 0; mi < 4; ++mi)
#pragma unroll
      for (int ni = 0; ni < 4; ++ni)
#pragma unroll
        for (int r = 0; r < 4; ++r) {
          const size_t idx = (size_t)(rbase + mi * 16 + rr + r) * ldc + (cbase + ni * 16 + cc);
          C[idx] = acc[mi][ni][r] + resid[idx];
        }
  }
}

// ---------------------------------------------------------------------------
// PREP (fused): pool(x1)->x1fT bf16 | transpose(x2)->x2fT bf16 | W->bf16
// 1-D grid: [0,3072) pool, [3072,6144) x2t, [6144,6720) wconv. block 256.
__global__ __launch_bounds__(256) void prep_kernel(
    const float* __restrict__ x1, const float* __restrict__ x2,
    const float* __restrict__ Wq, const float* __restrict__ Wk,
    const float* __restrict__ Wv, unsigned short* __restrict__ x1fT,
    unsigned short* __restrict__ x2fT, unsigned short* __restrict__ Wqb,
    unsigned short* __restrict__ Wkb, unsigned short* __restrict__ Wvb) {
  const int tid = threadIdx.x;
  __shared__ float tile[64][33];
  int id = blockIdx.x;
  if (id < 3072) {
    // ---- pool: 4x4 mean of x1[b][c][128][128] -> x1fT[(b*1024+n)][c] bf16
    const int c0 = (id % 12) * 64;
    const int ho = (id / 12) % 32;
    const int b = id / 384;
    const int ci = tid >> 5, wo = tid & 31;
#pragma unroll 2
    for (int cc = 0; cc < 8; ++cc) {
      const int c = c0 + cc * 8 + ci;
      const float* base = x1 + ((size_t)(b * 768 + c) * 128 + ho * 4) * 128 + wo * 4;
      float s = 0.f;
#pragma unroll
      for (int i = 0; i < 4; ++i) {
        f32x4 v = *reinterpret_cast<const f32x4*>(base + (size_t)i * 128);
        s += v[0] + v[1] + v[2] + v[3];
      }
      tile[cc * 8 + ci][wo] = s * 0.0625f;
    }
    __syncthreads();
    const int wo2 = tid >> 3, cg = tid & 7;
    uint4 pk;
    pk.x = (unsigned)f2b(tile[cg * 8 + 0][wo2]) | ((unsigned)f2b(tile[cg * 8 + 1][wo2]) << 16);
    pk.y = (unsigned)f2b(tile[cg * 8 + 2][wo2]) | ((unsigned)f2b(tile[cg * 8 + 3][wo2]) << 16);
    pk.z = (unsigned)f2b(tile[cg * 8 + 4][wo2]) | ((unsigned)f2b(tile[cg * 8 + 5][wo2]) << 16);
    pk.w = (unsigned)f2b(tile[cg * 8 + 6][wo2]) | ((unsigned)f2b(tile[cg * 8 + 7][wo2]) << 16);
    *reinterpret_cast<uint4*>(&x1fT[(size_t)(b * 1024 + ho * 32 + wo2) * 768 + c0 + cg * 8]) = pk;
  } else if (id < 6144) {
    // ---- x2 transpose: x2[b][c][n] -> x2fT[(b*1024+n)][c] bf16
    id -= 3072;
    const int ct = id % 12;
    const int nt = (id / 12) % 32;
    const int b = id / 384;
    {
      const int nl = tid & 31, cb = tid >> 5;
#pragma unroll
      for (int p = 0; p < 8; ++p) {
        const int cl = p * 8 + cb;
        tile[cl][nl] = x2[(size_t)(b * 768 + ct * 64 + cl) * 1024 + nt * 32 + nl];
      }
    }
    __syncthreads();
    {
      const int c2 = tid & 63, nb = tid >> 6;
#pragma unroll
      for (int p = 0; p < 8; ++p) {
        const int nl = p * 4 + nb;
        x2fT[(size_t)(b * 1024 + nt * 32 + nl) * 768 + ct * 64 + c2] = f2b(tile[c2][nl]);
      }
    }
  } else {
    // ---- weight convert f32->bf16, 16B stores
    const int i = (id - 6144) * 256 + tid;
    f32x4 a = reinterpret_cast<const f32x4*>(Wq)[i];
    f32x4 b = reinterpret_cast<const f32x4*>(Wk)[i];
    f32x4 c = reinterpret_cast<const f32x4*>(Wv)[i];
    uint2 oa, ob, oc;
    oa.x = (unsigned)f2b(a[0]) | ((unsigned)f2b(a[1]) << 16);
    oa.y = (unsigned)f2b(a[2]) | ((unsigned)f2b(a[3]) << 16);
    ob.x = (unsigned)f2b(b[0]) | ((unsigned)f2b(b[1]) << 16);
    ob.y = (unsigned)f2b(b[2]) | ((unsigned)f2b(b[3]) << 16);
    oc.x = (unsigned)f2b(c[0]) | ((unsigned)f2b(c[1]) << 16);
    oc.y = (unsigned)f2b(c[2]) | ((unsigned)f2b(c[3]) << 16);
    reinterpret_cast<uint2*>(Wqb)[i] = oa;
    reinterpret_cast<uint2*>(Wkb)[i] = ob;
    reinterpret_cast<uint2*>(Wvb)[i] = oc;
  }
}

// ---------------------------------------------------------------------------
// QKV (fused, one dispatch = 1152 blocks, 3 blocks/CU):
//  [0,384):   k  = Wk * x1f    -> kb  [768][8192]
//  [384,768): q  = Wq * x2f    -> qb  [768][8192]
//  [768,1152):vT = x1fT * Wv^T -> vTb [8192][768]
__global__ __launch_bounds__(256, 3) void qkv_kernel(
    const unsigned short* __restrict__ Wkb, const unsigned short* __restrict__ Wqb,
    const unsigned short* __restrict__ Wvb, const unsigned short* __restrict__ x1fT,
    const unsigned short* __restrict__ x2fT, unsigned short* __restrict__ kb,
    unsigned short* __restrict__ qb, unsigned short* __restrict__ vTb) {
  __shared__ unsigned short lds[3 * 8192];  // 3 ring buffers x (A 8KB + B 8KB)
  int id = blockIdx.x;
  if (id < 384) {
    gemm_body<0>(Wkb, x1fT, kb, nullptr, id >> 6, id & 63, 768, 768, 768, 8192, 1.f, lds);
  } else if (id < 768) {
    id -= 384;
    gemm_body<0>(Wqb, x2fT, qb, nullptr, id >> 6, id & 63, 768, 768, 768, 8192, 1.f, lds);
  } else {
    id -= 768;
    gemm_body<0>(x1fT, Wvb, vTb, nullptr, id / 6, id % 6, 768, 768, 768, 768, 1.f, lds);
  }
}

// attn partials: p[kh][b] = q[b][:, kh*512:+512] * k[b][:, kh*512:+512]^T / 32
// grid (6,6,16): z = kh*8 + b. Split-K=2 -> 576 blocks, 16 iters each.
__global__ __launch_bounds__(256, 3) void attn_kernel(const unsigned short* __restrict__ qb,
                                                      const unsigned short* __restrict__ kb,
                                                      float* __restrict__ attnp) {
  __shared__ unsigned short lds[3 * 8192];
  const int z = blockIdx.z;
  const int b = z & 7, kh = z >> 3;
  gemm_body<1>(qb + b * 1024 + kh * 512, kb + b * 1024 + kh * 512,
               attnp + (size_t)z * 589824, nullptr, blockIdx.y, blockIdx.x, 512, 8192,
               8192, 768, 1.f / 32.f, lds);
}

// out[b] = attn[b] * v[b] + x2[b]   [768][1024] f32 -> d_out
__global__ __launch_bounds__(256, 3) void out_kernel(const unsigned short* __restrict__ attnb,
                                                     const unsigned short* __restrict__ vTb,
                                                     float* __restrict__ out,
                                                     const float* __restrict__ x2) {
  __shared__ unsigned short lds[3 * 8192];
  const int bz = blockIdx.z;
  gemm_body<2>(attnb + (size_t)bz * 589824, vTb + (size_t)bz * 786432,
               out + (size_t)bz * 786432, x2 + (size_t)bz * 786432, blockIdx.y, blockIdx.x,
               768, 768, 768, 1024, 1.f, lds);
}

// ---------------------------------------------------------------------------
// Row softmax over summed split-K partials: S = p0 + p1 (already scaled),
// [6144 rows][768] f32 -> P bf16, one wave per row.
__global__ __launch_bounds__(256) void softmax_kernel(const float* __restrict__ S,
                                                      unsigned short* __restrict__ P) {
  const int row = blockIdx.x * 4 + (threadIdx.x >> 6);
  const int lane = threadIdx.x & 63;
  const float* r0 = S + (size_t)row * 768;
  const float* r1 = r0 + (size_t)8 * 589824;  // second K-half partial
  f32x4 v[3];
  float mx = -1e30f;
#pragma unroll
  for (int i = 0; i < 3; ++i) {
    f32x4 a = *reinterpret_cast<const f32x4*>(r0 + (i * 64 + lane) * 4);
    f32x4 b = *reinterpret_cast<const f32x4*>(r1 + (i * 64 + lane) * 4);
    v[i][0] = a[0] + b[0]; v[i][1] = a[1] + b[1];
    v[i][2] = a[2] + b[2]; v[i][3] = a[3] + b[3];
    mx = fmaxf(fmaxf(fmaxf(v[i][0], v[i][1]), fmaxf(v[i][2], v[i][3])), mx);
  }
#pragma unroll
  for (int off = 32; off > 0; off >>= 1) mx = fmaxf(mx, __shfl_xor(mx, off));
  float sum = 0.f;
#pragma unroll
  for (int i = 0; i < 3; ++i)
#pragma unroll
    for (int j = 0; j < 4; ++j) {
      v[i][j] = __expf(v[i][j] - mx);
      sum += v[i][j];
    }
#pragma unroll
  for (int off = 32; off > 0; off >>= 1) sum += __shfl_xor(sum, off);
  const float inv = 1.f / sum;
  unsigned short* p = P + (size_t)row * 768;
#pragma unroll
  for (int i = 0; i < 3; ++i) {
    uint2 o;
    o.x = (unsigned)f2b(v[i][0] * inv) | ((unsigned)f2b(v[i][1] * inv) << 16);
    o.y = (unsigned)f2b(v[i][2] * inv) | ((unsigned)f2b(v[i][3] * inv) << 16);
    *reinterpret_cast<uint2*>(p + (i * 64 + lane) * 4) = o;
  }
}

// ---------------------------------------------------------------------------
extern "C" void kernel_launch(void* const* d_in, const int* in_sizes, int n_in,
                              void* d_out, int out_size, void* d_ws, size_t ws_size,
                              hipStream_t stream) {
  const float* x1 = (const float*)d_in[0];  // [8][768][128][128]
  const float* x2 = (const float*)d_in[1];  // [8][768][32][32]
  const float* Wq = (const float*)d_in[2];  // [768][768]
  const float* Wk = (const float*)d_in[3];
  const float* Wv = (const float*)d_in[4];
  float* out = (float*)d_out;  // [8][768][32][32]

  char* ws = (char*)d_ws;
  size_t off = 0;
  auto alloc = [&](size_t bytes) {
    char* p = ws + off;
    off += (bytes + 255) & ~(size_t)255;
    return p;
  };
  unsigned short* x1fT = (unsigned short*)alloc((size_t)8192 * 768 * 2);  // [b*n][c1]
  unsigned short* x2fT = (unsigned short*)alloc((size_t)8192 * 768 * 2);  // [b*n][c2]
  unsigned short* Wqb = (unsigned short*)alloc((size_t)589824 * 2);
  unsigned short* Wkb = (unsigned short*)alloc((size_t)589824 * 2);
  unsigned short* Wvb = (unsigned short*)alloc((size_t)589824 * 2);
  unsigned short* qb = (unsigned short*)alloc((size_t)768 * 8192 * 2);   // [c2][b*n]
  unsigned short* kb = (unsigned short*)alloc((size_t)768 * 8192 * 2);   // [c1][b*n]
  unsigned short* vTb = (unsigned short*)alloc((size_t)8192 * 768 * 2);  // [b*n][c1]
  float* attnp = (float*)alloc((size_t)2 * 8 * 768 * 768 * 4);           // [kh][b][c2][c1]
  unsigned short* attnb = x2fT;  // overlay: x2fT dead after q-GEMM

  // 1. prep: pool x1, transpose x2, convert weights (all independent, one dispatch)
  prep_kernel<<<dim3(6720), 256, 0, stream>>>(x1, x2, Wq, Wk, Wv, x1fT, x2fT, Wqb, Wkb, Wvb);
  // 2. q/k/vT GEMMs in one dispatch (1152 blocks, 3/CU)
  qkv_kernel<<<dim3(1152), 256, 0, stream>>>(Wkb, Wqb, Wvb, x1fT, x2fT, kb, qb, vTb);
  // 3. attn partials (split-K=2, 576 blocks)
  attn_kernel<<<dim3(6, 6, 16), 256, 0, stream>>>(qb, kb, attnp);
  // 4. softmax over summed partials -> bf16 (into dead x2fT)
  softmax_kernel<<<dim3(1536), 256, 0, stream>>>(attnp, attnb);
  // 5. out = attn v + x2
  out_kernel<<<dim3(8, 6, 8), 256, 0, stream>>>(attnb, vTb, out, x2);
}